// Round 9
// baseline (133.586 us; speedup 1.0000x reference)
//
#include <hip/hip_runtime.h>
#include <hip/hip_bf16.h>
#include <math.h>

#define B_    64
#define TQ    32
#define TD    4096
#define HDIM  300
#define NB    29      // histogram bins
#define NFEAT 30      // 29 bins + exact-match feature
#define DTILE 256
#define NCHUNK 16     // TD / DTILE
#define KC    48      // k per chunk = 3 ktiles of 16
#define NKC   7       // chunks (KPAD = 336, zero-padded past 300)
#define KT    3       // ktiles per chunk
#define NF4C  12      // float4 per chunk per row
#define THREADS 256

typedef _Float16 half4 __attribute__((ext_vector_type(4)));
typedef float    f32x4 __attribute__((ext_vector_type(4)));

// bin upper bounds: jnp.linspace(-1,1,30)[1:], ub[k] = -1 + 2(k+1)/29
__device__ __forceinline__ float ubf(int k) {
    return (float)(-1.0 + (2.0 * (double)(k + 1)) / 29.0);
}

// bin one similarity value into the per-block LDS histogram
__device__ __forceinline__ void bin_one(float sim, unsigned* s_hist, int q) {
    if (sim > 0.999f && sim < 1.001f) {
        // only exact token matches land here; true sim < 1.0 strictly -> bin 28
        atomicAdd(&s_hist[q * NFEAT + 28], 1u);
        atomicAdd(&s_hist[q * NFEAT + 29], 1u);   // exact-match feature
    } else {
        int idx = (int)((sim + 1.0f) * 14.5f);    // guess, then exact fixup
        idx = idx < 0 ? 0 : (idx > NB ? NB : idx);
        while (idx < NB && sim >= ubf(idx)) ++idx;
        while (idx > 0 && sim < ubf(idx - 1)) --idx;
        if (idx < NB) atomicAdd(&s_hist[q * NFEAT + idx], 1u);
    }
}

// ---------------- q pre-pass: gather q rows ONCE per batch -> fp16 A-frags ----
// Grid 64 blocks x 64 threads. Thread (row = t&31, half = t>>5) stages half the
// k-range of q-row `row`: fp32 loads, exact fp32 norm partial, fp16 fragment
// stores to ws in the same per-chunk LDS image k_main will load linearly:
//   chunk c, slot (kt*2+tile)*64 + lane, lane = (row&15)+16*g, tile = row>>4.
__global__ void k_qfrag(const int* __restrict__ qsent, const float* __restrict__ emb,
                        _Float16* __restrict__ qf, float* __restrict__ invq) {
    const int b = blockIdx.x;
    const int t = threadIdx.x;
    const int row = t & 31, half = t >> 5;
    __shared__ float pn[2][TQ];
    const int tok = qsent[b * TQ + row];
    const float* p = emb + (size_t)tok * HDIM;
    _Float16* qfb = qf + (size_t)b * (NKC * KT * 2 * 64 * 4);
    float n = 0.f;
    for (int i = 0; i < 42; ++i) {                 // jf = half*42 + i in [0,84)
        const int jf = half * 42 + i;
        const int kg = jf * 4;
        float4 v = make_float4(0.f, 0.f, 0.f, 0.f);
        if (kg < 297) v = *(const float4*)(p + kg);    // kg<=296 -> covers <=299
        n = fmaf(v.x, v.x, n); n = fmaf(v.y, v.y, n);
        n = fmaf(v.z, v.z, n); n = fmaf(v.w, v.w, n);
        half4 h = {(_Float16)v.x, (_Float16)v.y, (_Float16)v.z, (_Float16)v.w};
        const int c = jf / NF4C, j = jf % NF4C, kt = j >> 2, g = j & 3;
        const int slot = c * (KT * 2 * 64) + (kt * 2 + (row >> 4)) * 64 + (row & 15) + 16 * g;
        *(half4*)&qfb[slot * 4] = h;
    }
    pn[half][row] = n;
    __syncthreads();
    if (half == 0) {
        float s = pn[0][row] + pn[1][row];
        invq[b * TQ + row] = 1.0f / (sqrtf(s + 1e-7f) + 1e-7f);
    }
}

// ---------------- main: fused d-norms + fp16-MFMA sim + histogram -------------
// 256 threads = 4 waves; tile 32q x 256d; K in 7 chunks of 48 (3 ktiles).
// v_mfma_f32_16x16x16f16, canonical layout (verified r8):
//   A lane l: A[l%16][(l/16)*4+j]  B lane l: B[(l/16)*4+j][l%16]  D: D[(l/16)*4+r][l%16]
// Staging: thread t owns d-row t; next chunk's 12 float4 prefetched into regs
// (T14) so gather latency hides under MFMA. A-frags come from the k_qfrag image
// in ws via linear 16B loads (L2/L3-hot). LDS ~33.7 KB -> 4 blocks/CU.
// VGPR-cap empirics on this hipcc: (N,2) -> 128-VGPR cap, no spills (r4/r6-r8);
// (N,4) -> 64-cap and catastrophic spills (r3/r5). Keep (THREADS,2).
__global__ __launch_bounds__(THREADS, 2) void k_main(
        const int* __restrict__ sent, const float* __restrict__ emb,
        const _Float16* __restrict__ qf, const float* __restrict__ invq,
        unsigned* __restrict__ ghist) {
    __shared__ __align__(16) _Float16 bfr[KT * 16 * 64 * 4];  // 24 KB B-frags (d)
    __shared__ __align__(16) _Float16 afr[KT * 2  * 64 * 4];  // 3 KB  A-frags (q)
    __shared__ int      toks[DTILE];
    __shared__ float    s_iq[TQ];
    __shared__ float    s_id[DTILE];
    __shared__ unsigned s_hist[TQ * NFEAT];

    const int b    = blockIdx.x >> 4;
    const int d0   = (blockIdx.x & 15) * DTILE;
    const int tid  = threadIdx.x;
    const int wid  = tid >> 6;
    const int lane = tid & 63;

    toks[tid] = sent[b * TD + d0 + tid];
    if (tid < TQ) s_iq[tid] = invq[b * TQ + tid];
    __syncthreads();

    const float* dptr = emb + (size_t)toks[tid] * HDIM;
    const float4* qfp = (const float4*)(qf + (size_t)b * (NKC * KT * 2 * 64 * 4));
    const int tile_d  = tid >> 4;          // 0..15
    const int l16     = tid & 15;

    float nd = 0.f;                        // exact fp32 d-norm (k-ascending)

    f32x4 acc[2][4];                       // [mtile][ntile]
#pragma unroll
    for (int mt = 0; mt < 2; ++mt)
#pragma unroll
        for (int nt = 0; nt < 4; ++nt) acc[mt][nt] = (f32x4){0.f, 0.f, 0.f, 0.f};

    // ---- prefetch chunk 0 d-rows (all 12 in range: k 0..47)
    float4 dreg[NF4C];
#pragma unroll
    for (int jf = 0; jf < NF4C; ++jf) dreg[jf] = *(const float4*)(dptr + jf * 4);

    for (int c = 0; c < NKC; ++c) {
        // ---- A-frags: linear cooperative load from ws (384 half4 slots = 192 b128)
        if (tid < 192) {
            float4 qa = qfp[c * 192 + tid];
            *(float4*)&afr[tid * 8] = qa;
        }
        // ---- write prefetched d-rows as fp16 frags + fp32 norm
#pragma unroll
        for (int jf = 0; jf < NF4C; ++jf) {
            float4 v = dreg[jf];
            nd = fmaf(v.x, v.x, nd); nd = fmaf(v.y, v.y, nd);
            nd = fmaf(v.z, v.z, nd); nd = fmaf(v.w, v.w, nd);
            half4 h = {(_Float16)v.x, (_Float16)v.y, (_Float16)v.z, (_Float16)v.w};
            const int kt = jf >> 2, g = jf & 3;
            *(half4*)&bfr[(((kt * 16 + tile_d) * 64) + l16 + 16 * g) * 4] = h;
        }
        // ---- prefetch next chunk's d-rows (in flight across MFMA phase)
        if (c + 1 < NKC) {
            const float* p = dptr + (c + 1) * KC;
            if (c + 1 < NKC - 1) {
#pragma unroll
                for (int jf = 0; jf < NF4C; ++jf) dreg[jf] = *(const float4*)(p + jf * 4);
            } else {               // last chunk: k 288..299 real, rest zero-pad
#pragma unroll
                for (int jf = 0; jf < NF4C; ++jf)
                    dreg[jf] = (jf < 3) ? *(const float4*)(p + jf * 4)
                                        : make_float4(0.f, 0.f, 0.f, 0.f);
            }
        }
        __syncthreads();

        // ---- MFMA: wave w owns ntiles w*4..w*4+3, both mtiles
#pragma unroll
        for (int kt = 0; kt < KT; ++kt) {
            half4 a0 = *(const half4*)&afr[((kt * 2 + 0) * 64 + lane) * 4];
            half4 a1 = *(const half4*)&afr[((kt * 2 + 1) * 64 + lane) * 4];
#pragma unroll
            for (int nt = 0; nt < 4; ++nt) {
                half4 bv = *(const half4*)&bfr[((kt * 16 + wid * 4 + nt) * 64 + lane) * 4];
                acc[0][nt] = __builtin_amdgcn_mfma_f32_16x16x16f16(a0, bv, acc[0][nt], 0, 0, 0);
                acc[1][nt] = __builtin_amdgcn_mfma_f32_16x16x16f16(a1, bv, acc[1][nt], 0, 0, 0);
            }
        }
        __syncthreads();   // before next chunk overwrites frags
    }

    // ---- finalize d-norms, init hist
    s_id[tid] = 1.0f / (sqrtf(nd + 1e-7f) + 1e-7f);
    for (int i = tid; i < TQ * NFEAT; i += THREADS) s_hist[i] = 0u;
    __syncthreads();

    // ---- epilogue: sim -> bins (fully static indexing)
    {
        const int qg = (lane >> 4) * 4;
#pragma unroll
        for (int nt = 0; nt < 4; ++nt) {
            const int d = (wid * 4 + nt) * 16 + (lane & 15);
            if (toks[d] == 0) continue;    // masked doc: +1e7 -> dropped everywhere
            const float idv = s_id[d];
#pragma unroll
            for (int mt = 0; mt < 2; ++mt) {
#pragma unroll
                for (int r = 0; r < 4; ++r) {
                    const int q = mt * 16 + qg + r;
                    bin_one(acc[mt][nt][r] * s_iq[q] * idv, s_hist, q);
                }
            }
        }
    }
    __syncthreads();
    for (int i = tid; i < TQ * NFEAT; i += THREADS) {
        unsigned v = s_hist[i];
        if (v) atomicAdd(&ghist[b * TQ * NFEAT + i], v);
    }
}

// ---------------- finish: log + MLP + gate softmax ----------------
__global__ void k_finish(const unsigned* __restrict__ ghist,
                         const int* __restrict__ qsent, const float* __restrict__ idf,
                         const float* __restrict__ w1, const float* __restrict__ b1,
                         const float* __restrict__ w2, const float* __restrict__ b2,
                         const float* __restrict__ gw, const float* __restrict__ ow,
                         const float* __restrict__ ob, float* __restrict__ out) {
    int b = blockIdx.x;
    int lane = threadIdx.x;   // 64 threads, lanes 0..31 active
    float ffw = 0.f;
    float logit = -3.0e38f;
    if (lane < TQ) {
        const unsigned* h = ghist + (b * TQ + lane) * NFEAT;
        float f[NFEAT];
        for (int k = 0; k < NFEAT; ++k) f[k] = logf((float)h[k] + 1.0f);
        float s2 = b2[0];
        for (int n = 0; n < 5; ++n) {
            float s = b1[n];
            for (int k = 0; k < NFEAT; ++k) s = fmaf(f[k], w1[k * 5 + n], s);
            s2 = fmaf(tanhf(s), w2[n], s2);
        }
        ffw = tanhf(s2);
        int qt = qsent[b * TQ + lane];
        logit = idf[b * TQ + lane] * gw[0] + (qt == 0 ? -1e7f : 0.f);
    }
    float m = logit;
#pragma unroll
    for (int t = 1; t < 64; t <<= 1) m = fmaxf(m, __shfl_xor(m, t, 64));
    float e = expf(logit - m);            // inactive lanes -> exp(-inf) = 0
    float se = e, sw = e * ffw;
#pragma unroll
    for (int t = 1; t < 64; t <<= 1) {
        se += __shfl_xor(se, t, 64);
        sw += __shfl_xor(sw, t, 64);
    }
    if (lane == 0) out[b] = (sw / se) * ow[0] + ob[0];
}

extern "C" void kernel_launch(void* const* d_in, const int* in_sizes, int n_in,
                              void* d_out, int out_size, void* d_ws, size_t ws_size,
                              hipStream_t stream) {
    const int*   sent  = (const int*)d_in[0];
    const int*   qsent = (const int*)d_in[1];
    const float* idf   = (const float*)d_in[2];
    const float* emb   = (const float*)d_in[3];
    const float* w1    = (const float*)d_in[4];
    const float* b1    = (const float*)d_in[5];
    const float* w2    = (const float*)d_in[6];
    const float* b2    = (const float*)d_in[7];
    const float* gw    = (const float*)d_in[8];
    const float* ow    = (const float*)d_in[9];
    const float* ob    = (const float*)d_in[10];
    float* out = (float*)d_out;

    char* ws = (char*)d_ws;
    unsigned*  ghist = (unsigned*)ws;                       // 240 KB
    _Float16*  qfrag = (_Float16*)(ws + (256 << 10));       // 64 * 21504 B = 1.34 MB
    float*     invq  = (float*)(ws + (256 << 10) + (size_t)B_ * NKC * KT * 2 * 64 * 4 * 2);

    hipMemsetAsync(ghist, 0, (size_t)B_ * TQ * NFEAT * 4, stream);
    k_qfrag<<<B_, 64, 0, stream>>>(qsent, emb, qfrag, invq);
    k_main<<<B_ * NCHUNK, THREADS, 0, stream>>>(sent, emb, qfrag, invq, ghist);
    k_finish<<<B_, 64, 0, stream>>>(ghist, qsent, idf, w1, b1, w2, b2, gw, ow, ob, out);
}

// Round 10
// 132.720 us; speedup vs baseline: 1.0065x; 1.0065x over previous
//
#include <hip/hip_runtime.h>
#include <hip/hip_bf16.h>
#include <math.h>

#define B_    64
#define TQ    32
#define TD    4096
#define HDIM  300
#define NB    29      // histogram bins
#define NFEAT 30      // 29 bins + exact-match feature
#define DTILE 256
#define NCHUNK 16     // TD / DTILE
#define KC    32      // k per chunk = 2 ktiles of 16
#define NKC   10      // chunks (KPAD = 320, zero-padded past 300)
#define KT    2       // ktiles per chunk
#define THREADS 256
#define QF_SLOTS (NKC * KT * 2 * 64)      // half4 slots per batch = 2560
#define QF_BYTES (QF_SLOTS * 8)           // 20480 B per batch

typedef _Float16 half4 __attribute__((ext_vector_type(4)));
typedef float    f32x4 __attribute__((ext_vector_type(4)));

// bin upper bounds: jnp.linspace(-1,1,30)[1:], ub[k] = -1 + 2(k+1)/29
__device__ __forceinline__ float ubf(int k) {
    return (float)(-1.0 + (2.0 * (double)(k + 1)) / 29.0);
}

// bin one similarity value into the per-block LDS histogram
__device__ __forceinline__ void bin_one(float sim, unsigned* s_hist, int q) {
    if (sim > 0.999f && sim < 1.001f) {
        // only exact token matches land here; true sim < 1.0 strictly -> bin 28
        atomicAdd(&s_hist[q * NFEAT + 28], 1u);
        atomicAdd(&s_hist[q * NFEAT + 29], 1u);   // exact-match feature
    } else {
        int idx = (int)((sim + 1.0f) * 14.5f);    // guess, then exact fixup
        idx = idx < 0 ? 0 : (idx > NB ? NB : idx);
        while (idx < NB && sim >= ubf(idx)) ++idx;
        while (idx > 0 && sim < ubf(idx - 1)) --idx;
        if (idx < NB) atomicAdd(&s_hist[q * NFEAT + idx], 1u);
    }
}

// ---------------- q pre-pass: gather q rows ONCE per batch -> fp16 A-frags ----
// Grid 64 x 64. Thread (row=t&31, half=t>>5): fp32 loads, exact fp32 norm
// partials, fp16 fragment stores in the per-chunk image k_main copies to LDS:
//   chunk c, slot c*256 + (kt*2 + row>>4)*64 + (row&15) + 16*g   (A unswizzled)
__global__ void k_qfrag(const int* __restrict__ qsent, const float* __restrict__ emb,
                        _Float16* __restrict__ qf, float* __restrict__ invq) {
    const int b = blockIdx.x;
    const int t = threadIdx.x;
    const int row = t & 31, half = t >> 5;
    __shared__ float pn[2][TQ];
    const int tok = qsent[b * TQ + row];
    const float* p = emb + (size_t)tok * HDIM;
    _Float16* qfb = qf + (size_t)b * (QF_SLOTS * 4);
    float n = 0.f;
    for (int i = 0; i < 40; ++i) {                 // jf = half*40 + i in [0,80)
        const int jf = half * 40 + i;
        const int kg = jf * 4;
        float4 v = make_float4(0.f, 0.f, 0.f, 0.f);
        if (kg < 297) v = *(const float4*)(p + kg);    // kg<=296 covers k<=299
        n = fmaf(v.x, v.x, n); n = fmaf(v.y, v.y, n);
        n = fmaf(v.z, v.z, n); n = fmaf(v.w, v.w, n);
        half4 h = {(_Float16)v.x, (_Float16)v.y, (_Float16)v.z, (_Float16)v.w};
        const int c = jf >> 3, j = jf & 7, kt = j >> 2, g = j & 3;
        const int slot = c * (KT * 2 * 64) + (kt * 2 + (row >> 4)) * 64 + (row & 15) + 16 * g;
        *(half4*)&qfb[slot * 4] = h;
    }
    pn[half][row] = n;
    __syncthreads();
    if (half == 0) {
        float s = pn[0][row] + pn[1][row];
        invq[b * TQ + row] = 1.0f / (sqrtf(s + 1e-7f) + 1e-7f);
    }
}

// ---------------- main: fused d-norms + fp16-MFMA sim + histogram -------------
// 256 threads = 4 waves; tile 32q x 256d; K in 10 chunks of 32 (2 ktiles).
// v_mfma_f32_16x16x16f16, canonical layout (verified r8):
//   A lane l: A[l%16][(l/16)*4+j]  B lane l: B[(l/16)*4+j][l%16]  D: D[(l/16)*4+r][l%16]
// COALESCED gather: wave w owns d-rows w*64..+63; per instruction 8 lanes x
// 8 rows -> each instr reads 128 B contiguous per row (~8-16 cache lines vs 64
// for thread-per-row; TA transaction count was the r9 bottleneck). Lane role:
// rsub=lane>>3 (row in group of 8), jsl=lane&7 (float4 slot, 32 k per chunk).
// Next chunk prefetched into 8 regs (T14). Norms: 8 per-lane partials +
// 3-step shfl_xor tree (deterministic).
// bfr LDS XOR-swizzle o^=((g&1)<<3) on write AND read: the 8 (kt,g) writers of
// one row would otherwise share a bank pair (8-way); swizzle restores the
// 4-lane/pair floor. A-frags stay unswizzled (reads already at floor).
// Single-arg launch_bounds: the 2nd arg empirically CAPS occupancy at arg
// waves/EU on this hipcc (r4/r6/r9 all ~25% regardless of LDS) and caps VGPR
// at 256/arg (r3/r5 spills). Need ~90 VGPR < 128 -> 4 waves/SIMD, LDS ~25 KB
// -> 4 blocks/CU resident.
__global__ __launch_bounds__(THREADS) void k_main(
        const int* __restrict__ sent, const float* __restrict__ emb,
        const _Float16* __restrict__ qf, const float* __restrict__ invq,
        unsigned* __restrict__ ghist) {
    __shared__ __align__(16) _Float16 bfr[KT * 16 * 64 * 4];  // 16 KB B-frags (d)
    __shared__ __align__(16) _Float16 afr[KT * 2  * 64 * 4];  // 2 KB  A-frags (q)
    __shared__ int      toks[DTILE];
    __shared__ float    s_iq[TQ];
    __shared__ float    s_id[DTILE];
    __shared__ unsigned s_hist[TQ * NFEAT];

    const int b    = blockIdx.x >> 4;
    const int d0   = (blockIdx.x & 15) * DTILE;
    const int tid  = threadIdx.x;
    const int wid  = tid >> 6;
    const int lane = tid & 63;

    toks[tid] = sent[b * TD + d0 + tid];
    if (tid < TQ) s_iq[tid] = invq[b * TQ + tid];
    __syncthreads();

    // staging roles: 8 lanes per row, 8 rows per instruction
    const int wbase = wid * 64;
    const int rsub  = lane >> 3;         // row within group of 8
    const int jsl   = lane & 7;          // float4 slot within chunk (k = jsl*4)
    const int kts   = jsl >> 2;          // ktile of this slot
    const int gs    = jsl & 3;           // k-group of this slot
    int rowv[8];
    const float* rp[8];
#pragma unroll
    for (int i = 0; i < 8; ++i) {
        rowv[i] = wbase + i * 8 + rsub;
        rp[i] = emb + (size_t)toks[rowv[i]] * HDIM + jsl * 4;
    }
    float ndv[8];
#pragma unroll
    for (int i = 0; i < 8; ++i) ndv[i] = 0.f;

    const float4* qfp = (const float4*)(qf + (size_t)b * (QF_SLOTS * 4));
    const int swl = lane ^ (((lane >> 4) & 1) << 3);   // B-read swizzle

    f32x4 acc[2][4];                       // [mtile][ntile]
#pragma unroll
    for (int mt = 0; mt < 2; ++mt)
#pragma unroll
        for (int nt = 0; nt < 4; ++nt) acc[mt][nt] = (f32x4){0.f, 0.f, 0.f, 0.f};

    // ---- prefetch chunk 0 (k 0..31, all valid)
    float4 dreg[8];
#pragma unroll
    for (int i = 0; i < 8; ++i) dreg[i] = *(const float4*)(rp[i]);

    for (int c = 0; c < NKC; ++c) {
        // ---- A-frags: linear cooperative load from ws (256 half4 = 128 b128)
        if (tid < 128) *(float4*)&afr[tid * 8] = qfp[c * 128 + tid];
        // ---- write prefetched d-rows as swizzled fp16 frags + fp32 norm partials
#pragma unroll
        for (int i = 0; i < 8; ++i) {
            float4 v = dreg[i];
            ndv[i] = fmaf(v.x, v.x, ndv[i]); ndv[i] = fmaf(v.y, v.y, ndv[i]);
            ndv[i] = fmaf(v.z, v.z, ndv[i]); ndv[i] = fmaf(v.w, v.w, ndv[i]);
            half4 h = {(_Float16)v.x, (_Float16)v.y, (_Float16)v.z, (_Float16)v.w};
            const int T = rowv[i] >> 4;
            const int o = ((rowv[i] & 15) ^ (8 * (gs & 1))) + 16 * gs;
            *(half4*)&bfr[((kts * 16 + T) * 64 + o) * 4] = h;
        }
        // ---- prefetch next chunk (in flight across MFMA phase)
        if (c + 1 < NKC) {
            const int kb2 = (c + 1) * KC;
            if (c + 1 < NKC - 1) {
#pragma unroll
                for (int i = 0; i < 8; ++i) dreg[i] = *(const float4*)(rp[i] + kb2);
            } else {               // last chunk: k 288..299 real, rest zero
                const bool val = (kb2 + jsl * 4) < 297;
#pragma unroll
                for (int i = 0; i < 8; ++i)
                    dreg[i] = val ? *(const float4*)(rp[i] + kb2)
                                  : make_float4(0.f, 0.f, 0.f, 0.f);
            }
        }
        __syncthreads();

        // ---- MFMA: wave w owns ntiles w*4..w*4+3, both mtiles
#pragma unroll
        for (int kt = 0; kt < KT; ++kt) {
            half4 a0 = *(const half4*)&afr[((kt * 2 + 0) * 64 + lane) * 4];
            half4 a1 = *(const half4*)&afr[((kt * 2 + 1) * 64 + lane) * 4];
#pragma unroll
            for (int nt = 0; nt < 4; ++nt) {
                half4 bv = *(const half4*)&bfr[((kt * 16 + wid * 4 + nt) * 64 + swl) * 4];
                acc[0][nt] = __builtin_amdgcn_mfma_f32_16x16x16f16(a0, bv, acc[0][nt], 0, 0, 0);
                acc[1][nt] = __builtin_amdgcn_mfma_f32_16x16x16f16(a1, bv, acc[1][nt], 0, 0, 0);
            }
        }
        __syncthreads();   // before next chunk overwrites frags
    }

    // ---- finalize d-norms: 8-lane tree reduce (deterministic), init hist
#pragma unroll
    for (int i = 0; i < 8; ++i) {
        float s = ndv[i];
        s += __shfl_xor(s, 1, 64);
        s += __shfl_xor(s, 2, 64);
        s += __shfl_xor(s, 4, 64);
        if (jsl == 0) s_id[rowv[i]] = 1.0f / (sqrtf(s + 1e-7f) + 1e-7f);
    }
    for (int i = tid; i < TQ * NFEAT; i += THREADS) s_hist[i] = 0u;
    __syncthreads();

    // ---- epilogue: sim -> bins (fully static indexing)
    {
        const int qg = (lane >> 4) * 4;
#pragma unroll
        for (int nt = 0; nt < 4; ++nt) {
            const int d = (wid * 4 + nt) * 16 + (lane & 15);
            if (toks[d] == 0) continue;    // masked doc: +1e7 -> dropped everywhere
            const float idv = s_id[d];
#pragma unroll
            for (int mt = 0; mt < 2; ++mt) {
#pragma unroll
                for (int r = 0; r < 4; ++r) {
                    const int q = mt * 16 + qg + r;
                    bin_one(acc[mt][nt][r] * s_iq[q] * idv, s_hist, q);
                }
            }
        }
    }
    __syncthreads();
    for (int i = tid; i < TQ * NFEAT; i += THREADS) {
        unsigned v = s_hist[i];
        if (v) atomicAdd(&ghist[b * TQ * NFEAT + i], v);
    }
}

// ---------------- finish: log + MLP + gate softmax ----------------
__global__ void k_finish(const unsigned* __restrict__ ghist,
                         const int* __restrict__ qsent, const float* __restrict__ idf,
                         const float* __restrict__ w1, const float* __restrict__ b1,
                         const float* __restrict__ w2, const float* __restrict__ b2,
                         const float* __restrict__ gw, const float* __restrict__ ow,
                         const float* __restrict__ ob, float* __restrict__ out) {
    int b = blockIdx.x;
    int lane = threadIdx.x;   // 64 threads, lanes 0..31 active
    float ffw = 0.f;
    float logit = -3.0e38f;
    if (lane < TQ) {
        const unsigned* h = ghist + (b * TQ + lane) * NFEAT;
        float f[NFEAT];
        for (int k = 0; k < NFEAT; ++k) f[k] = logf((float)h[k] + 1.0f);
        float s2 = b2[0];
        for (int n = 0; n < 5; ++n) {
            float s = b1[n];
            for (int k = 0; k < NFEAT; ++k) s = fmaf(f[k], w1[k * 5 + n], s);
            s2 = fmaf(tanhf(s), w2[n], s2);
        }
        ffw = tanhf(s2);
        int qt = qsent[b * TQ + lane];
        logit = idf[b * TQ + lane] * gw[0] + (qt == 0 ? -1e7f : 0.f);
    }
    float m = logit;
#pragma unroll
    for (int t = 1; t < 64; t <<= 1) m = fmaxf(m, __shfl_xor(m, t, 64));
    float e = expf(logit - m);            // inactive lanes -> exp(-inf) = 0
    float se = e, sw = e * ffw;
#pragma unroll
    for (int t = 1; t < 64; t <<= 1) {
        se += __shfl_xor(se, t, 64);
        sw += __shfl_xor(sw, t, 64);
    }
    if (lane == 0) out[b] = (sw / se) * ow[0] + ob[0];
}

extern "C" void kernel_launch(void* const* d_in, const int* in_sizes, int n_in,
                              void* d_out, int out_size, void* d_ws, size_t ws_size,
                              hipStream_t stream) {
    const int*   sent  = (const int*)d_in[0];
    const int*   qsent = (const int*)d_in[1];
    const float* idf   = (const float*)d_in[2];
    const float* emb   = (const float*)d_in[3];
    const float* w1    = (const float*)d_in[4];
    const float* b1    = (const float*)d_in[5];
    const float* w2    = (const float*)d_in[6];
    const float* b2    = (const float*)d_in[7];
    const float* gw    = (const float*)d_in[8];
    const float* ow    = (const float*)d_in[9];
    const float* ob    = (const float*)d_in[10];
    float* out = (float*)d_out;

    char* ws = (char*)d_ws;
    unsigned*  ghist = (unsigned*)ws;                       // 240 KB
    _Float16*  qfrag = (_Float16*)(ws + (256 << 10));       // 64 * 20480 B = 1.31 MB
    float*     invq  = (float*)(ws + (256 << 10) + (size_t)B_ * QF_BYTES);

    hipMemsetAsync(ghist, 0, (size_t)B_ * TQ * NFEAT * 4, stream);
    k_qfrag<<<B_, 64, 0, stream>>>(qsent, emb, qfrag, invq);
    k_main<<<B_ * NCHUNK, THREADS, 0, stream>>>(sent, emb, qfrag, invq, ghist);
    k_finish<<<B_, 64, 0, stream>>>(ghist, qsent, idf, w1, b1, w2, b2, gw, ow, ob, out);
}

// Round 11
// 96.323 us; speedup vs baseline: 1.3868x; 1.3779x over previous
//
#include <hip/hip_runtime.h>
#include <hip/hip_bf16.h>
#include <math.h>

#define B_    64
#define TQ    32
#define TD    4096
#define HDIM  300
#define NB    29      // histogram bins
#define NFEAT 30      // 29 bins + exact-match feature
#define NKT   19      // ktiles of 16 (K padded 300 -> 304)
#define THREADS 256
#define DPB   64      // d-rows per block (4 waves x 16)
#define QF_SLOTS (NKT * 2 * 64)        // half4 A-frag slots per batch = 2432
#define QF_F4    (QF_SLOTS / 2)        // = 1216 float4
#define QF_BYTES (QF_SLOTS * 8)        // 19456 B per batch

typedef _Float16 half4 __attribute__((ext_vector_type(4)));
typedef float    f32x4 __attribute__((ext_vector_type(4)));

// bin upper bounds: jnp.linspace(-1,1,30)[1:], ub[k] = -1 + 2(k+1)/29
__device__ __forceinline__ float ubf(int k) {
    return (float)(-1.0 + (2.0 * (double)(k + 1)) / 29.0);
}

// bin one similarity value into the per-block LDS histogram
__device__ __forceinline__ void bin_one(float sim, unsigned* s_hist, int q) {
    if (sim > 0.999f && sim < 1.001f) {
        // only exact token matches land here; true sim < 1.0 strictly -> bin 28
        atomicAdd(&s_hist[q * NFEAT + 28], 1u);
        atomicAdd(&s_hist[q * NFEAT + 29], 1u);   // exact-match feature
    } else {
        int idx = (int)((sim + 1.0f) * 14.5f);    // guess, then exact fixup
        idx = idx < 0 ? 0 : (idx > NB ? NB : idx);
        while (idx < NB && sim >= ubf(idx)) ++idx;
        while (idx > 0 && sim < ubf(idx - 1)) --idx;
        if (idx < NB) atomicAdd(&s_hist[q * NFEAT + idx], 1u);
    }
}

// ---------------- q pre-pass: gather q rows ONCE per batch -> fp16 A-frags ----
// Grid 64 x 64. Thread (row=t&31, half=t>>5): fp32 loads, exact fp32 norm
// partials (2-partial deterministic sum), fp16 A-fragment stores:
//   A lane l holds A[l%16][(l/16)*4+j]  =>  slot (kt*2 + row>>4)*64 + (row&15) + 16*g
__global__ void k_qfrag(const int* __restrict__ qsent, const float* __restrict__ emb,
                        _Float16* __restrict__ qf, float* __restrict__ invq) {
    const int b = blockIdx.x;
    const int t = threadIdx.x;
    const int row = t & 31, half = t >> 5;
    __shared__ float pn[2][TQ];
    const int tok = qsent[b * TQ + row];
    const float* p = emb + (size_t)tok * HDIM;
    _Float16* qfb = qf + (size_t)b * (QF_SLOTS * 4);
    float n = 0.f;
    for (int i = 0; i < 38; ++i) {                 // jf = half*38 + i in [0,76)
        const int jf = half * 38 + i;
        const int kg = jf * 4;
        float4 v = make_float4(0.f, 0.f, 0.f, 0.f);
        if (kg < 297) v = *(const float4*)(p + kg);    // kg<=296 covers k<=299
        n = fmaf(v.x, v.x, n); n = fmaf(v.y, v.y, n);
        n = fmaf(v.z, v.z, n); n = fmaf(v.w, v.w, n);
        half4 h = {(_Float16)v.x, (_Float16)v.y, (_Float16)v.z, (_Float16)v.w};
        const int kt = jf >> 2, g = jf & 3;
        const int slot = (kt * 2 + (row >> 4)) * 64 + (row & 15) + 16 * g;
        *(half4*)&qfb[slot * 4] = h;
    }
    pn[half][row] = n;
    __syncthreads();
    if (half == 0) {
        float s = pn[0][row] + pn[1][row];
        invq[b * TQ + row] = 1.0f / (sqrtf(s + 1e-7f) + 1e-7f);
    }
}

// ---------------- main: barrier-free register-streamed fp16-MFMA + histogram --
// Grid B_*64 blocks of 256 (4 waves); block = batch b, d-rows d0..d0+63;
// wave w owns rows w*16..+15 for ALL K. KEY: the 16x16x16f16 B-fragment is
// "lane l reads 4 consecutive k of d-row l%16" = 16 CONTIGUOUS BYTES of an emb
// row -> d goes global->reg->cvt->MFMA with NO LDS, NO transpose, NO barrier.
// Lane l streams row (lane&15), k-group g4=lane>>4, kt=0..18, ring prefetch
// depth 6 (in-flight ~6KB/wave; waves are fully independent streams).
// A-frags: staged once per block to LDS (19.5 KB), 2 conflict-free ds_read_b64
// per ktile. Only 2 __syncthreads total (post-A-stage, pre-hist-merge).
// acc = 8 VGPR (2 mtiles x f32x4); d-norms reduced in-register via shfl_xor
// (xor16 then xor32: deterministic); MFMA order identical to r8-r10.
__global__ __launch_bounds__(THREADS) void k_main(
        const int* __restrict__ sent, const float* __restrict__ emb,
        const _Float16* __restrict__ qf, const float* __restrict__ invq,
        unsigned* __restrict__ ghist) {
    __shared__ __align__(16) _Float16 afr[QF_SLOTS * 4];   // 19456 B A-frags
    __shared__ int      toks[DPB];
    __shared__ float    s_iq[TQ];
    __shared__ unsigned s_hist[TQ * NFEAT];

    const int b    = blockIdx.x >> 6;
    const int d0   = (blockIdx.x & 63) * DPB;
    const int tid  = threadIdx.x;
    const int wid  = tid >> 6;
    const int lane = tid & 63;

    if (tid < DPB) toks[tid] = sent[b * TD + d0 + tid];
    if (tid < TQ)  s_iq[tid] = invq[b * TQ + tid];
    for (int i = tid; i < TQ * NFEAT; i += THREADS) s_hist[i] = 0u;
    // ---- stage A-frags once (1216 float4, linear, L2-hot)
    {
        const float4* qfp = (const float4*)(qf + (size_t)b * (QF_SLOTS * 4));
        float4* afp = (float4*)afr;
        for (int i = tid; i < QF_F4; i += THREADS) afp[i] = qfp[i];
    }
    __syncthreads();

    // ---- per-lane stream setup
    const int g4   = lane >> 4;              // k-group 0..3
    const int rloc = wid * 16 + (lane & 15); // block-local d-row
    const int tok  = toks[rloc];
    const float* bp = emb + (size_t)tok * HDIM + g4 * 4;

    f32x4 acc0 = {0.f, 0.f, 0.f, 0.f};
    f32x4 acc1 = {0.f, 0.f, 0.f, 0.f};
    float nd = 0.f;

    // guarded B load: kt=18,g4=3 would read k 300..303 (OOB of row) -> zero
    auto ldB = [&](int kt) -> float4 {
        if (kt == 18 && g4 == 3) return make_float4(0.f, 0.f, 0.f, 0.f);
        return *(const float4*)(bp + kt * 16);
    };

    float4 pre[6];
#pragma unroll
    for (int p = 0; p < 6; ++p) pre[p] = ldB(p);

#pragma unroll
    for (int kt = 0; kt < NKT; ++kt) {
        float4 v = pre[kt % 6];
        if (kt + 6 < NKT) pre[kt % 6] = ldB(kt + 6);
        nd = fmaf(v.x, v.x, nd); nd = fmaf(v.y, v.y, nd);
        nd = fmaf(v.z, v.z, nd); nd = fmaf(v.w, v.w, nd);
        half4 hb = {(_Float16)v.x, (_Float16)v.y, (_Float16)v.z, (_Float16)v.w};
        half4 a0 = *(const half4*)&afr[((kt * 2 + 0) * 64 + lane) * 4];
        half4 a1 = *(const half4*)&afr[((kt * 2 + 1) * 64 + lane) * 4];
        acc0 = __builtin_amdgcn_mfma_f32_16x16x16f16(a0, hb, acc0, 0, 0, 0);
        acc1 = __builtin_amdgcn_mfma_f32_16x16x16f16(a1, hb, acc1, 0, 0, 0);
    }

    // ---- d-norm: sum 4 k-group partials (deterministic tree), stay in-register
    float s = nd;
    s += __shfl_xor(s, 16, 64);
    s += __shfl_xor(s, 32, 64);
    const float idv = 1.0f / (sqrtf(s + 1e-7f) + 1e-7f);

    // ---- epilogue: sim -> bins; lane's d-col = lane&15 = its own streamed row
    if (tok != 0) {            // masked doc: +1e7 -> dropped everywhere
#pragma unroll
        for (int r = 0; r < 4; ++r) {
            const int q0 = g4 * 4 + r;
            bin_one(acc0[r] * s_iq[q0] * idv, s_hist, q0);
            const int q1 = 16 + g4 * 4 + r;
            bin_one(acc1[r] * s_iq[q1] * idv, s_hist, q1);
        }
    }
    __syncthreads();
    for (int i = tid; i < TQ * NFEAT; i += THREADS) {
        unsigned v = s_hist[i];
        if (v) atomicAdd(&ghist[b * TQ * NFEAT + i], v);
    }
}

// ---------------- finish: log + MLP + gate softmax ----------------
__global__ void k_finish(const unsigned* __restrict__ ghist,
                         const int* __restrict__ qsent, const float* __restrict__ idf,
                         const float* __restrict__ w1, const float* __restrict__ b1,
                         const float* __restrict__ w2, const float* __restrict__ b2,
                         const float* __restrict__ gw, const float* __restrict__ ow,
                         const float* __restrict__ ob, float* __restrict__ out) {
    int b = blockIdx.x;
    int lane = threadIdx.x;   // 64 threads, lanes 0..31 active
    float ffw = 0.f;
    float logit = -3.0e38f;
    if (lane < TQ) {
        const unsigned* h = ghist + (b * TQ + lane) * NFEAT;
        float f[NFEAT];
        for (int k = 0; k < NFEAT; ++k) f[k] = logf((float)h[k] + 1.0f);
        float s2 = b2[0];
        for (int n = 0; n < 5; ++n) {
            float s = b1[n];
            for (int k = 0; k < NFEAT; ++k) s = fmaf(f[k], w1[k * 5 + n], s);
            s2 = fmaf(tanhf(s), w2[n], s2);
        }
        ffw = tanhf(s2);
        int qt = qsent[b * TQ + lane];
        logit = idf[b * TQ + lane] * gw[0] + (qt == 0 ? -1e7f : 0.f);
    }
    float m = logit;
#pragma unroll
    for (int t = 1; t < 64; t <<= 1) m = fmaxf(m, __shfl_xor(m, t, 64));
    float e = expf(logit - m);            // inactive lanes -> exp(-inf) = 0
    float se = e, sw = e * ffw;
#pragma unroll
    for (int t = 1; t < 64; t <<= 1) {
        se += __shfl_xor(se, t, 64);
        sw += __shfl_xor(sw, t, 64);
    }
    if (lane == 0) out[b] = (sw / se) * ow[0] + ob[0];
}

extern "C" void kernel_launch(void* const* d_in, const int* in_sizes, int n_in,
                              void* d_out, int out_size, void* d_ws, size_t ws_size,
                              hipStream_t stream) {
    const int*   sent  = (const int*)d_in[0];
    const int*   qsent = (const int*)d_in[1];
    const float* idf   = (const float*)d_in[2];
    const float* emb   = (const float*)d_in[3];
    const float* w1    = (const float*)d_in[4];
    const float* b1    = (const float*)d_in[5];
    const float* w2    = (const float*)d_in[6];
    const float* b2    = (const float*)d_in[7];
    const float* gw    = (const float*)d_in[8];
    const float* ow    = (const float*)d_in[9];
    const float* ob    = (const float*)d_in[10];
    float* out = (float*)d_out;

    char* ws = (char*)d_ws;
    unsigned*  ghist = (unsigned*)ws;                       // 240 KB
    _Float16*  qfrag = (_Float16*)(ws + (256 << 10));       // 64 * 19456 B = 1.24 MB
    float*     invq  = (float*)(ws + (256 << 10) + (size_t)B_ * QF_BYTES);

    hipMemsetAsync(ghist, 0, (size_t)B_ * TQ * NFEAT * 4, stream);
    k_qfrag<<<B_, 64, 0, stream>>>(qsent, emb, qfrag, invq);
    k_main<<<B_ * (TD / DPB), THREADS, 0, stream>>>(sent, emb, qfrag, invq, ghist);
    k_finish<<<B_, 64, 0, stream>>>(ghist, qsent, idf, w1, b1, w2, b2, gw, ow, ob, out);
}